// Round 10
// baseline (270.562 us; speedup 1.0000x reference)
//
#include <hip/hip_runtime.h>

#define NB 8192
#define NL 64
#define NH 128

typedef __bf16 bf16x8 __attribute__((ext_vector_type(8)));
typedef float f32x4 __attribute__((ext_vector_type(4)));
typedef unsigned uint4v __attribute__((ext_vector_type(4)));
typedef unsigned short ushort8 __attribute__((ext_vector_type(8)));

// phys->logical permutation for the h buffer (GEMM1 epilogue pair-packing):
// phys p = c*32 + 2e (+1) holds logical c*32 + e (+16)
__device__ __host__ __forceinline__ int p2l(int p) {
  return (p & ~31) + ((p & 1) << 4) + ((p & 31) >> 1);
}
// phys->logical permutation for x=concat(x1,x2) (x1x2 pair-packing):
// phys even p -> x1 col p/2 ; phys odd p -> x2 col p/2 (logical 64+p/2)
__device__ __host__ __forceinline__ int pi2(int p) {
  return (p & 1) ? 64 + (p >> 1) : (p >> 1);
}

__device__ __forceinline__ unsigned pk2(float lo, float hi) {
  union { __bf16 b[2]; unsigned u; } t;
  t.b[0] = (__bf16)lo; t.b[1] = (__bf16)hi;
  return t.u;
}

// ---------------------------------------------------------------------------
// Repack weights (f32 -> bf16 MFMA A-operand fragments).
// wp1: [layer3][ntile8][kstep4][lane64][reg8]; value = W1[l][srck][n]
//      srck = k (layer 0) | pi2(k) (layers 1,2)   [x-buffer phys layout]
// wp2: [layer3][ntile4][kstep4][lane64][reg8]; value = W2[l][p2l(k)][n]
// ---------------------------------------------------------------------------
__global__ __launch_bounds__(256) void repack_w(const float* __restrict__ W1,
                                                const float* __restrict__ W2,
                                                unsigned short* __restrict__ wp1,
                                                unsigned short* __restrict__ wp2) {
  int t = blockIdx.x * 256 + threadIdx.x;
  int lane = t & 63, g = t >> 6;
  if (g < 96) {                                   // W1: 3*8*4 groups
    int layer = g >> 5, rem = g & 31, nt = rem >> 2, ks = rem & 3;
    int n = nt * 16 + (lane & 15);
    int kb = ks * 32 + (lane >> 4) * 8;
    ushort8 v;
#pragma unroll
    for (int r = 0; r < 8; ++r) {
      int k = kb + r;
      int srck = (layer == 0) ? k : pi2(k);
      union { __bf16 b; unsigned short u; } c;
      c.b = (__bf16)W1[(layer * 128 + srck) * 128 + n];
      v[r] = c.u;
    }
    *reinterpret_cast<ushort8*>(wp1 + ((size_t)g * 64 + lane) * 8) = v;
  } else if (g < 144) {                           // W2: 3*4*4 groups, k by p2l
    int g2 = g - 96;
    int layer = g2 >> 4, rem = g2 & 15, nt = rem >> 2, ks = rem & 3;
    int n = nt * 16 + (lane & 15);
    int kb = ks * 32 + (lane >> 4) * 8;
    ushort8 v;
#pragma unroll
    for (int r = 0; r < 8; ++r) {
      union { __bf16 b; unsigned short u; } c;
      c.b = (__bf16)W2[(layer * 128 + p2l(kb + r)) * 64 + n];
      v[r] = c.u;
    }
    *reinterpret_cast<ushort8*>(wp2 + ((size_t)g2 * 64 + lane) * 8) = v;
  }
}

// ---------------------------------------------------------------------------
// Fused depth-3 MLP stack, ONE WAVE (64-thread block) per batch row.
// Private 16 KB xbuf per wave (10 blocks/CU = 160 KB). ZERO barriers:
// all ordering is same-wave lgkmcnt, scheduled fine-grained by the compiler
// instead of block-wide s_barrier drains (R5-R9 were ~85% barrier stall).
// h and x1x2 are staged in registers (bf16-packed) across chunk loops so the
// single xbuf can be updated in place. LN stats fully in-wave via shfl.
// xbuf: bf16 [64][128], swizzle byte ^= ((row&15)<<4).
// ---------------------------------------------------------------------------
__global__ __launch_bounds__(64) void fused_mlp(
    const float* __restrict__ hidden,
    const float* __restrict__ b1,
    const float* __restrict__ b2,
    const float* __restrict__ gamma,
    const float* __restrict__ beta,
    const unsigned short* __restrict__ wp1u,
    const unsigned short* __restrict__ wp2u,
    float* __restrict__ out) {
  __shared__ __align__(16) unsigned short xbuf[NL * NH];   // 16384 B
  const int lane = threadIdx.x;
  const int ci = lane & 15, lg = lane >> 4;
  char* xc = reinterpret_cast<char*>(xbuf);

  const int rbase = ci * 256;      // row = mt*16+ci byte base (mod mt*4096)
  const int rxor = ci << 4;        // 4-bit row swizzle for rows ≡ ci (mod 16)

  // ---- stage 0: load hidden[b] (f32) -> xbuf (bf16, swizzled, identity) ----
  const float* src = hidden + (size_t)blockIdx.x * (NL * NH);
#pragma unroll 1
  for (int i = 0; i < 16; ++i) {
    int f = i * 64 + lane;          // 8-elem chunk id, 0..1023
    int row = f >> 4;
    int cb = (f & 15) * 16;         // byte column
    const float4* p = reinterpret_cast<const float4*>(src + f * 8);
    float4 a = p[0], bq = p[1];
    bf16x8 v;
    v[0] = (__bf16)a.x;  v[1] = (__bf16)a.y;  v[2] = (__bf16)a.z;  v[3] = (__bf16)a.w;
    v[4] = (__bf16)bq.x; v[5] = (__bf16)bq.y; v[6] = (__bf16)bq.z; v[7] = (__bf16)bq.w;
    *reinterpret_cast<bf16x8*>(xc + row * 256 + (cb ^ ((row & 15) << 4))) = v;
  }

#pragma unroll 1
  for (int layer = 0; layer < 3; ++layer) {
    const unsigned short* wl1 = wp1u + (size_t)layer * 16384;

    // ===== GEMM1 (transposed): h^T = W1^T(A) x x(B); h staged in regs ======
    uint4v hpk[4][4];               // [chunk][mt]: bf16 pairs (n, n+16)
    float sum[4], sq[4];
#pragma unroll
    for (int mt = 0; mt < 4; ++mt) { sum[mt] = 0.f; sq[mt] = 0.f; }

#pragma unroll
    for (int c = 0; c < 4; ++c) {   // n-chunk: logical cols [c*32, c*32+32)
      bf16x8 w1f0[4], w1f1[4];
#pragma unroll
      for (int ks = 0; ks < 4; ++ks) {
        w1f0[ks] = *reinterpret_cast<const bf16x8*>(
            wl1 + (((c * 2 + 0) * 4 + ks) * 64 + lane) * 8);
        w1f1[ks] = *reinterpret_cast<const bf16x8*>(
            wl1 + (((c * 2 + 1) * 4 + ks) * 64 + lane) * 8);
      }
      f32x4 bA = *reinterpret_cast<const f32x4*>(b1 + layer * 128 + c * 32 + lg * 4);
      f32x4 bB = *reinterpret_cast<const f32x4*>(b1 + layer * 128 + c * 32 + 16 + lg * 4);
      f32x4 acc0[4], acc1[4];
#pragma unroll
      for (int mt = 0; mt < 4; ++mt) { acc0[mt] = bA; acc1[mt] = bB; }
#pragma unroll
      for (int ks = 0; ks < 4; ++ks) {
        int cbx = ((ks * 64 + lg * 16) ^ rxor) + rbase;
#pragma unroll
        for (int mt = 0; mt < 4; ++mt) {
          bf16x8 xf = *reinterpret_cast<const bf16x8*>(xc + mt * 4096 + cbx);
          acc0[mt] = __builtin_amdgcn_mfma_f32_16x16x32_bf16(w1f0[ks], xf, acc0[mt], 0, 0, 0);
          acc1[mt] = __builtin_amdgcn_mfma_f32_16x16x32_bf16(w1f1[ks], xf, acc1[mt], 0, 0, 0);
        }
      }
      // epilogue: accumulate LN stats (f32, pre-rounding) + pack h to regs
#pragma unroll
      for (int mt = 0; mt < 4; ++mt) {
        uint4v w;
#pragma unroll
        for (int r = 0; r < 4; ++r) {
          float a0 = acc0[mt][r], a1 = acc1[mt][r];
          sum[mt] += a0 + a1;
          sq[mt] = fmaf(a0, a0, fmaf(a1, a1, sq[mt]));
          w[r] = pk2(a0, a1);
        }
        hpk[c][mt] = w;
      }
    }

    // ===== LN stats finalize: fully in-wave (reduce over lg via shfl) ======
    float mu[4], rs[4];
#pragma unroll
    for (int mt = 0; mt < 4; ++mt) {
      float s = sum[mt], q = sq[mt];
      s += __shfl_xor(s, 16);  q += __shfl_xor(q, 16);
      s += __shfl_xor(s, 32);  q += __shfl_xor(q, 32);
      mu[mt] = s * (1.f / 128.f);
      float var = q * (1.f / 128.f) - mu[mt] * mu[mt];
      rs[mt] = rsqrtf(var + 1e-5f);
    }

    // ===== normalize + ReLU + write xn -> xbuf (in place; x consumed) ======
#pragma unroll
    for (int c = 0; c < 4; ++c) {
      f32x4 glo = *reinterpret_cast<const f32x4*>(gamma + layer * 128 + c * 32 + lg * 4);
      f32x4 ghi = *reinterpret_cast<const f32x4*>(gamma + layer * 128 + c * 32 + 16 + lg * 4);
      f32x4 tlo = *reinterpret_cast<const f32x4*>(beta + layer * 128 + c * 32 + lg * 4);
      f32x4 thi = *reinterpret_cast<const f32x4*>(beta + layer * 128 + c * 32 + 16 + lg * 4);
#pragma unroll
      for (int mt = 0; mt < 4; ++mt) {
        f32x4 alo = glo * rs[mt], ahi = ghi * rs[mt];
        f32x4 clo = tlo - alo * mu[mt], chi = thi - ahi * mu[mt];
        uint4v hw = hpk[c][mt], w;
#pragma unroll
        for (int r = 0; r < 4; ++r) {
          unsigned u = hw[r];
          float lo = __uint_as_float(u << 16);
          float hi = __uint_as_float(u & 0xffff0000u);
          float ylo = fmaxf(fmaf(lo, alo[r], clo[r]), 0.f);
          float yhi = fmaxf(fmaf(hi, ahi[r], chi[r]), 0.f);
          w[r] = pk2(ylo, yhi);
        }
        *reinterpret_cast<uint4v*>(
            xc + mt * 4096 + rbase + ((c * 64 + lg * 16) ^ rxor)) = w;
      }
    }

    // ===== GEMM2 (transposed): x1^T = W2^T(A) x xn(B); x1x2 staged in regs ==
    const unsigned short* wl2 = wp2u + (size_t)layer * 8192;
    uint4v xpk[4][4];               // [chunk][mt]: (x1, x2) packed dwords
#pragma unroll
    for (int c2 = 0; c2 < 4; ++c2) {   // n2-chunk: cols [c2*16, c2*16+16)
      bf16x8 w2f[4];
#pragma unroll
      for (int ks = 0; ks < 4; ++ks)
        w2f[ks] = *reinterpret_cast<const bf16x8*>(
            wl2 + ((c2 * 4 + ks) * 64 + lane) * 8);
      f32x4 b2v = *reinterpret_cast<const f32x4*>(b2 + layer * 64 + c2 * 16 + lg * 4);
      f32x4 acc2[4];
#pragma unroll
      for (int mt = 0; mt < 4; ++mt) acc2[mt] = b2v;
#pragma unroll
      for (int ks = 0; ks < 4; ++ks) {
        int cbx = ((ks * 64 + lg * 16) ^ rxor) + rbase;
#pragma unroll
        for (int mt = 0; mt < 4; ++mt) {
          bf16x8 xf = *reinterpret_cast<const bf16x8*>(xc + mt * 4096 + cbx);
          acc2[mt] = __builtin_amdgcn_mfma_f32_16x16x32_bf16(w2f[ks], xf, acc2[mt], 0, 0, 0);
        }
      }
      // max-pool over L: in-reg over mt, then over ci lanes (shfl 1,2,4,8)
      f32x4 mm;
#pragma unroll
      for (int r = 0; r < 4; ++r)
        mm[r] = fmaxf(fmaxf(acc2[0][r], acc2[1][r]), fmaxf(acc2[2][r], acc2[3][r]));
#pragma unroll
      for (int o = 1; o < 16; o <<= 1)
#pragma unroll
        for (int r = 0; r < 4; ++r) mm[r] = fmaxf(mm[r], __shfl_xor(mm[r], o));

      if (layer < 2) {
#pragma unroll
        for (int mt = 0; mt < 4; ++mt) {
          uint4v w;
#pragma unroll
          for (int r = 0; r < 4; ++r) w[r] = pk2(acc2[mt][r], mm[r]);
          xpk[c2][mt] = w;
        }
      } else {
        // final output (f32): out[b] = [x2_3, x2_3]; mm[r] holds n2=c2*16+lg*4+r
        if (ci == 0) {
          float* o = out + (size_t)blockIdx.x * 128 + c2 * 16 + lg * 4;
          *reinterpret_cast<f32x4*>(o) = mm;
          *reinterpret_cast<f32x4*>(o + 64) = mm;
        }
      }
    }
    if (layer < 2) {
      // write next x = (x1,x2) pack -> xbuf (in place; xn consumed)
#pragma unroll
      for (int c2 = 0; c2 < 4; ++c2)
#pragma unroll
        for (int mt = 0; mt < 4; ++mt)
          *reinterpret_cast<uint4v*>(
              xc + mt * 4096 + rbase + ((c2 * 64 + lg * 16) ^ rxor)) = xpk[c2][mt];
    }
  }
}

extern "C" void kernel_launch(void* const* d_in, const int* in_sizes, int n_in,
                              void* d_out, int out_size, void* d_ws, size_t ws_size,
                              hipStream_t stream) {
  const float* hidden = (const float*)d_in[0];
  const float* W1 = (const float*)d_in[1];
  const float* b1 = (const float*)d_in[2];
  const float* gamma = (const float*)d_in[3];
  const float* beta = (const float*)d_in[4];
  const float* W2 = (const float*)d_in[5];
  const float* b2 = (const float*)d_in[6];
  (void)in_sizes; (void)n_in; (void)out_size; (void)ws_size;

  unsigned short* wp1 = (unsigned short*)d_ws;          // 49152 ushorts
  unsigned short* wp2 = wp1 + 3 * 8 * 4 * 64 * 8;       // 24576 ushorts
  float* out = (float*)d_out;

  repack_w<<<36, 256, 0, stream>>>(W1, W2, wp1, wp2);
  fused_mlp<<<NB, 64, 0, stream>>>(hidden, b1, b2, gamma, beta, wp1, wp2, out);
}

// Round 11
// 265.090 us; speedup vs baseline: 1.0206x; 1.0206x over previous
//
#include <hip/hip_runtime.h>

#define NB 8192

typedef __bf16 bf16x8 __attribute__((ext_vector_type(8)));
typedef float f32x4 __attribute__((ext_vector_type(4)));
typedef unsigned uint4v __attribute__((ext_vector_type(4)));
typedef unsigned short ushort8 __attribute__((ext_vector_type(8)));

// Fragment-slot -> logical-feature bijection.
// B-frag slot k = ks*32 + lg*8 + j*4 + r  (ks=k[6:5], lg=k[4:3], j=k[2], r=k[1:0])
// holds the lane-local value with logical feature l = (2*ks+j)*16 + lg*4 + r,
// because the producing MFMA leaves output n = nt*16 + lg*4 + r in register
// (nt,r) of the same lane. Weights are repacked with srck = lmap(k) so the
// register file IS the next B operand (no shuffles, no LDS).
__device__ __host__ __forceinline__ int lmap(int k) {
  return (k >> 5) * 32 + ((k >> 2) & 1) * 16 + ((k >> 3) & 3) * 4 + (k & 3);
}

__device__ __forceinline__ unsigned pk2(float lo, float hi) {
  union { __bf16 b[2]; unsigned u; } t;
  t.b[0] = (__bf16)lo; t.b[1] = (__bf16)hi;
  return t.u;
}

// ---------------------------------------------------------------------------
// Repack weights (f32 -> bf16 MFMA A-operand fragments).
// wp1: [layer3][nt8][ks4][lane64][reg8]; value = W1[l][srck][n], n = nt*16+(lane&15)
//      srck = k (layer 0: x comes straight from hidden) | lmap(k) (layers 1,2)
// wp2: [layer3][nt4][ks4][lane64][reg8]; value = W2[l][lmap(k)][n]
// ---------------------------------------------------------------------------
__global__ __launch_bounds__(256) void repack_w(const float* __restrict__ W1,
                                                const float* __restrict__ W2,
                                                unsigned short* __restrict__ wp1,
                                                unsigned short* __restrict__ wp2) {
  int t = blockIdx.x * 256 + threadIdx.x;
  int lane = t & 63, g = t >> 6;
  if (g < 96) {                                   // W1: 3 layers * 8 nt * 4 ks
    int layer = g >> 5, rem = g & 31, nt = rem >> 2, ks = rem & 3;
    int n = nt * 16 + (lane & 15);
    int kb = ks * 32 + (lane >> 4) * 8;
    ushort8 v;
#pragma unroll
    for (int r = 0; r < 8; ++r) {
      int k = kb + r;
      int srck = (layer == 0) ? k : lmap(k);
      union { __bf16 b; unsigned short u; } c;
      c.b = (__bf16)W1[(layer * 128 + srck) * 128 + n];
      v[r] = c.u;
    }
    *reinterpret_cast<ushort8*>(wp1 + ((size_t)g * 64 + lane) * 8) = v;
  } else if (g < 144) {                           // W2: 3 layers * 4 nt * 4 ks
    int g2 = g - 96;
    int layer = g2 >> 4, rem = g2 & 15, nt = rem >> 2, ks = rem & 3;
    int n = nt * 16 + (lane & 15);
    int kb = ks * 32 + (lane >> 4) * 8;
    ushort8 v;
#pragma unroll
    for (int r = 0; r < 8; ++r) {
      union { __bf16 b; unsigned short u; } c;
      c.b = (__bf16)W2[(layer * 128 + lmap(kb + r)) * 64 + n];
      v[r] = c.u;
    }
    *reinterpret_cast<ushort8*>(wp2 + ((size_t)g2 * 64 + lane) * 8) = v;
  }
}

// ---------------------------------------------------------------------------
// Fused depth-3 MLP stack. One 4-wave block per batch row; wave owns 16 L-rows
// (L = wave*16 + ci). The activation tile NEVER touches LDS:
//   GEMM1 (transposed, W as A-operand): lane holds h[n][L=ci] for all 128 n
//   LN: reduce over n = in-lane 32 values + shfl_xor(16,32); normalize in regs
//   h-pack: registers are directly the GEMM2 B-fragment (lmap'd W2)
//   GEMM2: lane holds x1[n2][L=ci] for all 64 n2
//   pool over L: shfl_xor(1,2,4,8) + 1KB LDS cross-wave exchange (2 barriers)
//   next-layer x: registers are directly the GEMM1 B-fragment (lmap'd W1)
// Weights stream from L2/L1 as A-fragments (same addresses for all waves).
// ---------------------------------------------------------------------------
__global__ __launch_bounds__(256) void fused_mlp(
    const float* __restrict__ hidden,
    const float* __restrict__ b1,
    const float* __restrict__ b2,
    const float* __restrict__ gamma,
    const float* __restrict__ beta,
    const unsigned short* __restrict__ wp1u,
    const unsigned short* __restrict__ wp2u,
    float* __restrict__ out) {
  __shared__ __align__(16) float x2p[4][64];   // per-wave pool partials
  __shared__ __align__(16) float x2c[64];      // combined pooled max

  const int tid = threadIdx.x;
  const int wave = tid >> 6, lane = tid & 63;
  const int ci = lane & 15, lg = lane >> 4;

  // GEMM1 B operand: x[k][L=wave*16+ci], k = ks*32 + lg*8 + e  (bf16 pairs)
  uint4v xfrag[4];
  {
    const float* src = hidden + (size_t)blockIdx.x * (64 * 128)
                     + (wave * 16 + ci) * 128 + lg * 8;
#pragma unroll
    for (int ks = 0; ks < 4; ++ks) {
      float4 a = *reinterpret_cast<const float4*>(src + ks * 32);
      float4 b = *reinterpret_cast<const float4*>(src + ks * 32 + 4);
      uint4v v;
      v[0] = pk2(a.x, a.y); v[1] = pk2(a.z, a.w);
      v[2] = pk2(b.x, b.y); v[3] = pk2(b.z, b.w);
      xfrag[ks] = v;
    }
  }

#pragma unroll 1
  for (int layer = 0; layer < 3; ++layer) {
    // ===== GEMM1: h[n][L] = sum_k W1[k][n] x[k][L] + b1[n], all in regs =====
    const unsigned short* wl1 = wp1u + (size_t)layer * 16384;
    f32x4 acc[8];
#pragma unroll
    for (int nt = 0; nt < 8; ++nt)
      acc[nt] = *reinterpret_cast<const f32x4*>(b1 + layer * 128 + nt * 16 + lg * 4);
#pragma unroll
    for (int ks = 0; ks < 4; ++ks) {
      union { uint4v u; bf16x8 b; } xb; xb.u = xfrag[ks];
#pragma unroll
      for (int nt = 0; nt < 8; ++nt) {
        bf16x8 wf = *reinterpret_cast<const bf16x8*>(
            wl1 + ((nt * 4 + ks) * 64 + lane) * 8);
        acc[nt] = __builtin_amdgcn_mfma_f32_16x16x32_bf16(wf, xb.b, acc[nt], 0, 0, 0);
      }
    }

    // ===== LayerNorm stats: in-lane 32 + shfl over lg (row = L = ci) ========
    float s = 0.f, q = 0.f;
#pragma unroll
    for (int nt = 0; nt < 8; ++nt)
#pragma unroll
      for (int r = 0; r < 4; ++r) { float v = acc[nt][r]; s += v; q = fmaf(v, v, q); }
    s += __shfl_xor(s, 16);  q += __shfl_xor(q, 16);
    s += __shfl_xor(s, 32);  q += __shfl_xor(q, 32);
    const float mu = s * (1.f / 128.f);
    const float rsq = rsqrtf(q * (1.f / 128.f) - mu * mu + 1e-5f);

    // ===== normalize + ReLU + pack: registers become the GEMM2 B-frag =======
    uint4v bfragB[4];
#pragma unroll
    for (int ks = 0; ks < 4; ++ks) {
      uint4v w;
#pragma unroll
      for (int j = 0; j < 2; ++j) {
        const int nt = ks * 2 + j;
        f32x4 g4 = *reinterpret_cast<const f32x4*>(gamma + layer * 128 + nt * 16 + lg * 4);
        f32x4 t4 = *reinterpret_cast<const f32x4*>(beta + layer * 128 + nt * 16 + lg * 4);
        f32x4 a4 = g4 * rsq;
        f32x4 c4 = t4 - a4 * mu;
        float y0 = fmaxf(fmaf(acc[nt][0], a4[0], c4[0]), 0.f);
        float y1 = fmaxf(fmaf(acc[nt][1], a4[1], c4[1]), 0.f);
        float y2 = fmaxf(fmaf(acc[nt][2], a4[2], c4[2]), 0.f);
        float y3 = fmaxf(fmaf(acc[nt][3], a4[3], c4[3]), 0.f);
        w[j * 2 + 0] = pk2(y0, y1);
        w[j * 2 + 1] = pk2(y2, y3);
      }
      bfragB[ks] = w;
    }

    // ===== GEMM2: x1[n2][L] = sum_n W2[n][n2] xn[n][L] + b2[n2] =============
    const unsigned short* wl2 = wp2u + (size_t)layer * 8192;
    f32x4 acc2[4];
#pragma unroll
    for (int nt2 = 0; nt2 < 4; ++nt2)
      acc2[nt2] = *reinterpret_cast<const f32x4*>(b2 + layer * 64 + nt2 * 16 + lg * 4);
#pragma unroll
    for (int ks = 0; ks < 4; ++ks) {
      union { uint4v u; bf16x8 b; } xb; xb.u = bfragB[ks];
#pragma unroll
      for (int nt2 = 0; nt2 < 4; ++nt2) {
        bf16x8 wf = *reinterpret_cast<const bf16x8*>(
            wl2 + ((nt2 * 4 + ks) * 64 + lane) * 8);
        acc2[nt2] = __builtin_amdgcn_mfma_f32_16x16x32_bf16(wf, xb.b, acc2[nt2], 0, 0, 0);
      }
    }

    // ===== max-pool over L: in-wave over ci, then cross-wave via 1KB LDS ====
    f32x4 pm[4];
#pragma unroll
    for (int nt2 = 0; nt2 < 4; ++nt2) pm[nt2] = acc2[nt2];
#pragma unroll
    for (int o = 1; o < 16; o <<= 1)
#pragma unroll
      for (int nt2 = 0; nt2 < 4; ++nt2)
#pragma unroll
        for (int r = 0; r < 4; ++r)
          pm[nt2][r] = fmaxf(pm[nt2][r], __shfl_xor(pm[nt2][r], o));
    if (ci == 0) {
#pragma unroll
      for (int nt2 = 0; nt2 < 4; ++nt2)
        *reinterpret_cast<f32x4*>(&x2p[wave][nt2 * 16 + lg * 4]) = pm[nt2];
    }
    __syncthreads();  // pool partials visible

    if (layer == 2) {
      // final output (f32): out[b] = [x2_3, x2_3]
      if (tid < 64) {
        float v = fmaxf(fmaxf(x2p[0][tid], x2p[1][tid]),
                        fmaxf(x2p[2][tid], x2p[3][tid]));
        float* o = out + (size_t)blockIdx.x * 128 + tid;
        o[0] = v;
        o[64] = v;
      }
    } else {
      if (tid < 64)
        x2c[tid] = fmaxf(fmaxf(x2p[0][tid], x2p[1][tid]),
                         fmaxf(x2p[2][tid], x2p[3][tid]));
      __syncthreads();  // combined x2 visible
      // next-layer B-frag: ks 0,1 <- x1 (lane-local acc2); ks 2,3 <- x2c
#pragma unroll
      for (int ks = 0; ks < 2; ++ks) {
        uint4v w;
        w[0] = pk2(acc2[ks * 2][0], acc2[ks * 2][1]);
        w[1] = pk2(acc2[ks * 2][2], acc2[ks * 2][3]);
        w[2] = pk2(acc2[ks * 2 + 1][0], acc2[ks * 2 + 1][1]);
        w[3] = pk2(acc2[ks * 2 + 1][2], acc2[ks * 2 + 1][3]);
        xfrag[ks] = w;
      }
#pragma unroll
      for (int ks = 2; ks < 4; ++ks) {
        f32x4 m0 = *reinterpret_cast<const f32x4*>(&x2c[(ks - 2) * 32 + lg * 4]);
        f32x4 m1 = *reinterpret_cast<const f32x4*>(&x2c[(ks - 2) * 32 + 16 + lg * 4]);
        uint4v w;
        w[0] = pk2(m0[0], m0[1]); w[1] = pk2(m0[2], m0[3]);
        w[2] = pk2(m1[0], m1[1]); w[3] = pk2(m1[2], m1[3]);
        xfrag[ks] = w;
      }
    }
  }
}

extern "C" void kernel_launch(void* const* d_in, const int* in_sizes, int n_in,
                              void* d_out, int out_size, void* d_ws, size_t ws_size,
                              hipStream_t stream) {
  const float* hidden = (const float*)d_in[0];
  const float* W1 = (const float*)d_in[1];
  const float* b1 = (const float*)d_in[2];
  const float* gamma = (const float*)d_in[3];
  const float* beta = (const float*)d_in[4];
  const float* W2 = (const float*)d_in[5];
  const float* b2 = (const float*)d_in[6];
  (void)in_sizes; (void)n_in; (void)out_size; (void)ws_size;

  unsigned short* wp1 = (unsigned short*)d_ws;          // 49152 ushorts
  unsigned short* wp2 = wp1 + 3 * 8 * 4 * 64 * 8;       // 24576 ushorts
  float* out = (float*)d_out;

  repack_w<<<36, 256, 0, stream>>>(W1, W2, wp1, wp2);
  fused_mlp<<<NB, 256, 0, stream>>>(hidden, b1, b2, gamma, beta, wp1, wp2, out);
}

// Round 12
// 244.576 us; speedup vs baseline: 1.1063x; 1.0839x over previous
//
#include <hip/hip_runtime.h>

#define NB 8192

typedef __bf16 bf16x8 __attribute__((ext_vector_type(8)));
typedef float f32x4 __attribute__((ext_vector_type(4)));
typedef unsigned uint2v __attribute__((ext_vector_type(2)));
typedef unsigned uint4v __attribute__((ext_vector_type(4)));
typedef unsigned short ushort8 __attribute__((ext_vector_type(8)));

__device__ __forceinline__ unsigned pk2(float lo, float hi) {
  union { __bf16 b[2]; unsigned u; } t;
  t.b[0] = (__bf16)lo; t.b[1] = (__bf16)hi;
  return t.u;
}

// ---------------------------------------------------------------------------
// Repack weights (f32 -> bf16 MFMA A-operand fragments), NATURAL k order.
// (Transposed GEMMs with r-pair packing store h and concat(x1,x2) in natural
// feature order, so no k-permutations are needed anywhere.)
// wp1: [layer3][nt8][ks4][lane64][reg8]; value = W1[l][ks*32+(lane>>4)*8+r][nt*16+(lane&15)]
// wp2: [layer3][nt4][ks4][lane64][reg8]; same with W2 (n2 = nt*16+(lane&15))
// ---------------------------------------------------------------------------
__global__ __launch_bounds__(256) void repack_w(const float* __restrict__ W1,
                                                const float* __restrict__ W2,
                                                unsigned short* __restrict__ wp1,
                                                unsigned short* __restrict__ wp2) {
  int t = blockIdx.x * 256 + threadIdx.x;
  int lane = t & 63, g = t >> 6;
  if (g < 96) {                                   // W1: 3 layers * 8 nt * 4 ks
    int layer = g >> 5, rem = g & 31, nt = rem >> 2, ks = rem & 3;
    int n = nt * 16 + (lane & 15);
    int kb = ks * 32 + (lane >> 4) * 8;
    ushort8 v;
#pragma unroll
    for (int r = 0; r < 8; ++r) {
      union { __bf16 b; unsigned short u; } c;
      c.b = (__bf16)W1[(layer * 128 + kb + r) * 128 + n];
      v[r] = c.u;
    }
    *reinterpret_cast<ushort8*>(wp1 + ((size_t)g * 64 + lane) * 8) = v;
  } else if (g < 144) {                           // W2: 3 layers * 4 nt * 4 ks
    int g2 = g - 96;
    int layer = g2 >> 4, rem = g2 & 15, nt = rem >> 2, ks = rem & 3;
    int n = nt * 16 + (lane & 15);
    int kb = ks * 32 + (lane >> 4) * 8;
    ushort8 v;
#pragma unroll
    for (int r = 0; r < 8; ++r) {
      union { __bf16 b; unsigned short u; } c;
      c.b = (__bf16)W2[(layer * 128 + kb + r) * 64 + n];
      v[r] = c.u;
    }
    *reinterpret_cast<ushort8*>(wp2 + ((size_t)g2 * 64 + lane) * 8) = v;
  }
}

// ---------------------------------------------------------------------------
// Fused depth-3 MLP stack. One 8-WAVE block (512 threads) per batch row.
// Fine-grained wave tiles keep the register file small (target <=64 incl.
// unified AGPRs -> 8 waves/SIMD; R7's 4x8-col geometry was pinned at 4):
//   GEMM1 (transposed, W1 as A): wave w -> n-cols [w*16,+16), acc = 4xf32x4
//   LN: wave w -> rows [w*8,+8), 8 lanes/row, shfl_xor(1,2,4)
//   GEMM2 (transposed): 16 tasks (nt2 = w&3, Lt = (w>>2)*2+t), 1 f32x4 each
//   pool: shfl over ci + 1KB LDS partials
// h and x=concat(x1,x2) stored NATURAL [L][feature] bf16 in xB/xA,
// swizzle byte ^= ((row&15)<<4); epilogues are b64 r-pair-packed writes.
// No min-waves bound (R4/R6: forcing it spills).
// ---------------------------------------------------------------------------
__global__ __launch_bounds__(512) void fused_mlp(
    const float* __restrict__ hidden,
    const float* __restrict__ b1,
    const float* __restrict__ b2,
    const float* __restrict__ gamma,
    const float* __restrict__ beta,
    const unsigned short* __restrict__ wp1u,
    const unsigned short* __restrict__ wp2u,
    float* __restrict__ out) {
  __shared__ __align__(16) unsigned short xAu[64 * 128];   // 16384 B (x)
  __shared__ __align__(16) unsigned short xBu[64 * 128];   // 16384 B (h/xn)
  __shared__ __align__(16) float x2p[4][64];               // pool partials
  __shared__ __align__(16) float x2c[64];                  // combined pool

  const int tid = threadIdx.x;
  const int wave = tid >> 6, lane = tid & 63;
  const int ci = lane & 15, lg = lane >> 4;
  char* xA = reinterpret_cast<char*>(xAu);
  char* xB = reinterpret_cast<char*>(xBu);

  const int rbase = ci * 256;        // row = (tile)*16 + ci byte base
  const int rxor = ci << 4;          // swizzle bits for rows ≡ ci (mod 16)

  // ---- stage 0: load hidden[b] (f32) -> xA (bf16, swizzled, natural) ----
  const float* src = hidden + (size_t)blockIdx.x * (64 * 128);
#pragma unroll
  for (int i = 0; i < 2; ++i) {
    int f = i * 512 + tid;           // 8-elem chunk id, 0..1023
    int row = f >> 4;
    int cb = (f & 15) * 16;
    const float4* p = reinterpret_cast<const float4*>(src + f * 8);
    float4 a = p[0], bq = p[1];
    uint4v v;
    v[0] = pk2(a.x, a.y);  v[1] = pk2(a.z, a.w);
    v[2] = pk2(bq.x, bq.y); v[3] = pk2(bq.z, bq.w);
    *reinterpret_cast<uint4v*>(xA + row * 256 + (cb ^ ((row & 15) << 4))) = v;
  }
  __syncthreads();

#pragma unroll 1
  for (int layer = 0; layer < 3; ++layer) {
    // ===== GEMM1 (transposed): h[n][L], wave -> n-cols [wave*16,+16) =======
    const unsigned short* wl1 = wp1u + (size_t)layer * 16384 + (size_t)wave * 2048;
    f32x4 acc[4];
    {
      f32x4 bini = *reinterpret_cast<const f32x4*>(b1 + layer * 128 + wave * 16 + lg * 4);
#pragma unroll
      for (int mt = 0; mt < 4; ++mt) acc[mt] = bini;
    }
#pragma unroll
    for (int ks = 0; ks < 4; ++ks) {
      bf16x8 wf = *reinterpret_cast<const bf16x8*>(wl1 + (ks * 64 + lane) * 8);
      int cbx = ((ks * 64 + lg * 16) ^ rxor) + rbase;
#pragma unroll
      for (int mt = 0; mt < 4; ++mt) {
        bf16x8 xf = *reinterpret_cast<const bf16x8*>(xA + mt * 4096 + cbx);
        acc[mt] = __builtin_amdgcn_mfma_f32_16x16x32_bf16(wf, xf, acc[mt], 0, 0, 0);
      }
    }
    // writeback h -> xB natural: row L = mt*16+ci, cols wave*16+lg*4 (.. +3)
    {
      int cb = (wave * 32 + lg * 8) ^ rxor;   // byte col, r-pair packed
#pragma unroll
      for (int mt = 0; mt < 4; ++mt) {
        uint2v w;
        w[0] = pk2(acc[mt][0], acc[mt][1]);
        w[1] = pk2(acc[mt][2], acc[mt][3]);
        *reinterpret_cast<uint2v*>(xB + mt * 4096 + rbase + cb) = w;
      }
    }
    __syncthreads();  // β1: h visible

    // ===== LayerNorm + ReLU in place on xB: 8 lanes per row ================
    {
      const int row = wave * 8 + (lane >> 3);
      const int q = lane & 7;                  // 16-col chunk
      const int rb = row * 256, rx = (row & 15) << 4;
      bf16x8 h0 = *reinterpret_cast<const bf16x8*>(xB + rb + ((q * 32) ^ rx));
      bf16x8 h1 = *reinterpret_cast<const bf16x8*>(xB + rb + ((q * 32 + 16) ^ rx));
      float s = 0.f, qq = 0.f;
#pragma unroll
      for (int j = 0; j < 8; ++j) {
        float v0 = (float)h0[j], v1 = (float)h1[j];
        s += v0 + v1;
        qq = fmaf(v0, v0, fmaf(v1, v1, qq));
      }
      s += __shfl_xor(s, 1);  qq += __shfl_xor(qq, 1);
      s += __shfl_xor(s, 2);  qq += __shfl_xor(qq, 2);
      s += __shfl_xor(s, 4);  qq += __shfl_xor(qq, 4);
      float mu = s * (1.f / 128.f);
      float rs = rsqrtf(qq * (1.f / 128.f) - mu * mu + 1e-5f);
      const float* gl = gamma + layer * 128 + q * 16;
      const float* bl = beta + layer * 128 + q * 16;
#pragma unroll
      for (int h = 0; h < 2; ++h) {
        bf16x8 hv = h ? h1 : h0;
        f32x4 g0 = *reinterpret_cast<const f32x4*>(gl + h * 8);
        f32x4 g1 = *reinterpret_cast<const f32x4*>(gl + h * 8 + 4);
        f32x4 t0 = *reinterpret_cast<const f32x4*>(bl + h * 8);
        f32x4 t1 = *reinterpret_cast<const f32x4*>(bl + h * 8 + 4);
        uint4v y;
#pragma unroll
        for (int j2 = 0; j2 < 2; ++j2) {
          f32x4 gg = j2 ? g1 : g0, tt = j2 ? t1 : t0;
#pragma unroll
          for (int p = 0; p < 2; ++p) {
            float a0 = gg[p * 2] * rs, a1 = gg[p * 2 + 1] * rs;
            float c0 = tt[p * 2] - a0 * mu, c1 = tt[p * 2 + 1] - a1 * mu;
            float y0 = fmaxf(fmaf((float)hv[j2 * 4 + p * 2], a0, c0), 0.f);
            float y1 = fmaxf(fmaf((float)hv[j2 * 4 + p * 2 + 1], a1, c1), 0.f);
            y[j2 * 2 + p] = pk2(y0, y1);
          }
        }
        *reinterpret_cast<uint4v*>(xB + rb + ((q * 32 + h * 16) ^ rx)) = y;
      }
    }
    __syncthreads();  // β2: normalized h visible

    // ===== GEMM2 (transposed): x1[n2][L]; tasks (nt2=w&3, Lt=(w>>2)*2+t) ===
    const int nt2 = wave & 3;
    const int LtB = (wave >> 2) * 2;
    const unsigned short* wl2 = wp2u + (size_t)layer * 8192 + (size_t)nt2 * 2048;
    f32x4 acc2[2];
    {
      f32x4 b2i = *reinterpret_cast<const f32x4*>(b2 + layer * 64 + nt2 * 16 + lg * 4);
      acc2[0] = b2i; acc2[1] = b2i;
    }
#pragma unroll
    for (int ks = 0; ks < 4; ++ks) {
      bf16x8 wf = *reinterpret_cast<const bf16x8*>(wl2 + (ks * 64 + lane) * 8);
      int cbx = ((ks * 64 + lg * 16) ^ rxor) + rbase;
#pragma unroll
      for (int t = 0; t < 2; ++t) {
        bf16x8 xf = *reinterpret_cast<const bf16x8*>(xB + (LtB + t) * 4096 + cbx);
        acc2[t] = __builtin_amdgcn_mfma_f32_16x16x32_bf16(wf, xf, acc2[t], 0, 0, 0);
      }
    }

    // pool partials over each task's 16 L (shfl over ci), write 1KB LDS
#pragma unroll
    for (int t = 0; t < 2; ++t) {
      f32x4 pm = acc2[t];
#pragma unroll
      for (int o = 1; o < 16; o <<= 1)
#pragma unroll
        for (int r = 0; r < 4; ++r) pm[r] = fmaxf(pm[r], __shfl_xor(pm[r], o));
      if (ci == 0)
        *reinterpret_cast<f32x4*>(&x2p[LtB + t][nt2 * 16 + lg * 4]) = pm;
    }

    if (layer < 2) {
      // x1 -> xA cols [0,64): row L = (LtB+t)*16+ci, b64 r-pair packed
      int cb = (nt2 * 32 + lg * 8) ^ rxor;
#pragma unroll
      for (int t = 0; t < 2; ++t) {
        uint2v w;
        w[0] = pk2(acc2[t][0], acc2[t][1]);
        w[1] = pk2(acc2[t][2], acc2[t][3]);
        *reinterpret_cast<uint2v*>(xA + (LtB + t) * 4096 + rbase + cb) = w;
      }
      __syncthreads();  // β3: partials + x1 visible
      if (tid < 64)
        x2c[tid] = fmaxf(fmaxf(x2p[0][tid], x2p[1][tid]),
                         fmaxf(x2p[2][tid], x2p[3][tid]));
      __syncthreads();  // β4: x2c visible
      // broadcast x2 -> xA cols [64,128): 512 threads x 8 cols (b128)
      {
        int row = tid >> 3, c8 = (tid & 7) * 8;
        f32x4 m0 = *reinterpret_cast<const f32x4*>(x2c + c8);
        f32x4 m1 = *reinterpret_cast<const f32x4*>(x2c + c8 + 4);
        uint4v v;
        v[0] = pk2(m0[0], m0[1]); v[1] = pk2(m0[2], m0[3]);
        v[2] = pk2(m1[0], m1[1]); v[3] = pk2(m1[2], m1[3]);
        *reinterpret_cast<uint4v*>(
            xA + row * 256 + ((128 + c8 * 2) ^ ((row & 15) << 4))) = v;
      }
      __syncthreads();  // β5: new x complete
    } else {
      __syncthreads();  // β3: partials visible
      // final output (f32): out[b] = [x2_3, x2_3]
      if (tid < 64) {
        float v = fmaxf(fmaxf(x2p[0][tid], x2p[1][tid]),
                        fmaxf(x2p[2][tid], x2p[3][tid]));
        float* o = out + (size_t)blockIdx.x * 128 + tid;
        o[0] = v;
        o[64] = v;
      }
    }
  }
}

extern "C" void kernel_launch(void* const* d_in, const int* in_sizes, int n_in,
                              void* d_out, int out_size, void* d_ws, size_t ws_size,
                              hipStream_t stream) {
  const float* hidden = (const float*)d_in[0];
  const float* W1 = (const float*)d_in[1];
  const float* b1 = (const float*)d_in[2];
  const float* gamma = (const float*)d_in[3];
  const float* beta = (const float*)d_in[4];
  const float* W2 = (const float*)d_in[5];
  const float* b2 = (const float*)d_in[6];
  (void)in_sizes; (void)n_in; (void)out_size; (void)ws_size;

  unsigned short* wp1 = (unsigned short*)d_ws;          // 49152 ushorts
  unsigned short* wp2 = wp1 + 3 * 8 * 4 * 64 * 8;       // 24576 ushorts
  float* out = (float*)d_out;

  repack_w<<<36, 256, 0, stream>>>(W1, W2, wp1, wp2);
  fused_mlp<<<NB, 512, 0, stream>>>(hidden, b1, b2, gamma, beta, wp1, wp2, out);
}

// Round 14
// 158.998 us; speedup vs baseline: 1.7017x; 1.5382x over previous
//
#include <hip/hip_runtime.h>

#define NB 8192

typedef __bf16 bf16x8 __attribute__((ext_vector_type(8)));
typedef float f32x4 __attribute__((ext_vector_type(4)));
typedef unsigned uint4v __attribute__((ext_vector_type(4)));
typedef unsigned short ushort8 __attribute__((ext_vector_type(8)));

// phys->logical permutation for the h/xn buffer (pair-packed (n, n+16)):
// phys p = w*32 + 2e (+1) holds logical w*32 + e (+16)
__device__ __host__ __forceinline__ int p2l(int p) {
  return (p & ~31) + ((p & 1) << 4) + ((p & 31) >> 1);
}
// phys->logical permutation for x=concat(x1,x2) (pair-packed (x1, x2)):
// phys even p -> x1 col p/2 ; phys odd p -> x2 col p/2 (logical 64+p/2)
__device__ __host__ __forceinline__ int pi2(int p) {
  return (p & 1) ? 64 + (p >> 1) : (p >> 1);
}

__device__ __forceinline__ unsigned pk2(float lo, float hi) {
  union { __bf16 b[2]; unsigned u; } t;
  t.b[0] = (__bf16)lo; t.b[1] = (__bf16)hi;
  return t.u;
}

// ---------------------------------------------------------------------------
// Repack weights (f32 -> bf16 MFMA A-operand fragments). Same as R9/R13.
// wp1: [layer3][nt8][ks4][lane64][reg8]; value = W1[l][srck][n]
//      srck = k (layer 0) | pi2(k) (layers 1,2)   [x-buffer phys layout]
// wp2: [layer3][nt4][ks4][lane64][reg8]; value = W2[l][p2l(k)][n]
// ---------------------------------------------------------------------------
__global__ __launch_bounds__(256) void repack_w(const float* __restrict__ W1,
                                                const float* __restrict__ W2,
                                                unsigned short* __restrict__ wp1,
                                                unsigned short* __restrict__ wp2) {
  int t = blockIdx.x * 256 + threadIdx.x;
  int lane = t & 63, g = t >> 6;
  if (g < 96) {                                   // W1: 3 layers * 8 nt * 4 ks
    int layer = g >> 5, rem = g & 31, nt = rem >> 2, ks = rem & 3;
    int n = nt * 16 + (lane & 15);
    int kb = ks * 32 + (lane >> 4) * 8;
    ushort8 v;
#pragma unroll
    for (int r = 0; r < 8; ++r) {
      int k = kb + r;
      int srck = (layer == 0) ? k : pi2(k);
      union { __bf16 b; unsigned short u; } c;
      c.b = (__bf16)W1[(layer * 128 + srck) * 128 + n];
      v[r] = c.u;
    }
    *reinterpret_cast<ushort8*>(wp1 + ((size_t)g * 64 + lane) * 8) = v;
  } else if (g < 144) {                           // W2: 3 layers * 4 nt * 4 ks
    int g2 = g - 96;
    int layer = g2 >> 4, rem = g2 & 15, nt = rem >> 2, ks = rem & 3;
    int n = nt * 16 + (lane & 15);
    int kb = ks * 32 + (lane >> 4) * 8;
    ushort8 v;
#pragma unroll
    for (int r = 0; r < 8; ++r) {
      union { __bf16 b; unsigned short u; } c;
      c.b = (__bf16)W2[(layer * 128 + p2l(kb + r)) * 64 + n];
      v[r] = c.u;
    }
    *reinterpret_cast<ushort8*>(wp2 + ((size_t)g2 * 64 + lane) * 8) = v;
  }
}

// ---------------------------------------------------------------------------
// Fused depth-3 MLP stack, one 4-wave block per batch row.
// TRANSPOSED GEMMs (W as A-operand, R9-verified layouts). In-register LN:
//   stats: in-lane 8-val sums + shfl_xor(16,32) -> lg==0 lanes write plain
//   float partials ssum/qsum[wave][L]; after B1 EVERY lane sums the 4 wave
//   partials itself (broadcast ds_read_b32) and computes mu/rs locally.
//   (R13's wave0-combine + mursf relay produced absmax 0.164 — removed.)
//   normalize+ReLU in-reg -> ONE b128 xn write per mt.
// 3 barriers/layer. xA = x (pi2 phys), xB = xn (p2l phys), swizzle (row&15)<<4.
// No min-waves bound (R4/R6: forcing spills).
// ---------------------------------------------------------------------------
__global__ __launch_bounds__(256) void fused_mlp(
    const float* __restrict__ hidden,
    const float* __restrict__ b1,
    const float* __restrict__ b2,
    const float* __restrict__ gamma,
    const float* __restrict__ beta,
    const unsigned short* __restrict__ wp1u,
    const unsigned short* __restrict__ wp2u,
    float* __restrict__ out) {
  __shared__ __align__(16) unsigned short xAu[64 * 128];   // 16384 B (x)
  __shared__ __align__(16) unsigned short xBu[64 * 128];   // 16384 B (xn)
  __shared__ __align__(16) float ssum[4][64];              // 1024 B
  __shared__ __align__(16) float qsum[4][64];              // 1024 B

  const int tid = threadIdx.x;
  const int wave = tid >> 6, lane = tid & 63;
  const int ci = lane & 15, lg = lane >> 4;
  char* xA = reinterpret_cast<char*>(xAu);
  char* xB = reinterpret_cast<char*>(xBu);

  const int rbase = ci * 256;      // B-frag read: row = mt*16+ci
  const int rxor = ci << 4;
  // b128 writeback base: row = mt*16+ci, phys dwords wave*16+lg*4 .. +3
  const int wbase = ci * 256 + ((wave * 64 + lg * 16) ^ rxor);

  // ---- stage 0: load hidden[b] (f32) -> xA (bf16, swizzled, natural) ----
  const float* src = hidden + (size_t)blockIdx.x * (64 * 128);
#pragma unroll
  for (int i = 0; i < 4; ++i) {
    int f = i * 256 + tid;
    int row = f >> 4;
    int cb = (f & 15) * 16;
    const float4* p = reinterpret_cast<const float4*>(src + f * 8);
    float4 a = p[0], bq = p[1];
    uint4v v;
    v[0] = pk2(a.x, a.y);  v[1] = pk2(a.z, a.w);
    v[2] = pk2(bq.x, bq.y); v[3] = pk2(bq.z, bq.w);
    *reinterpret_cast<uint4v*>(xA + row * 256 + (cb ^ ((row & 15) << 4))) = v;
  }
  __syncthreads();

#pragma unroll 1
  for (int layer = 0; layer < 3; ++layer) {
    // ===== GEMM1 (transposed): acc[mt][h][r] = h[L=mt*16+ci][n=wave*32+h*16+lg*4+r]
    const unsigned short* wl1 = wp1u + (size_t)layer * 16384;
    f32x4 bA = *reinterpret_cast<const f32x4*>(b1 + layer * 128 + wave * 32 + lg * 4);
    f32x4 bB = *reinterpret_cast<const f32x4*>(b1 + layer * 128 + wave * 32 + 16 + lg * 4);
    f32x4 acc[4][2];
#pragma unroll
    for (int mt = 0; mt < 4; ++mt) { acc[mt][0] = bA; acc[mt][1] = bB; }
#pragma unroll
    for (int ks = 0; ks < 4; ++ks) {
      bf16x8 bf0 = *reinterpret_cast<const bf16x8*>(
          wl1 + (((wave * 2 + 0) * 4 + ks) * 64 + lane) * 8);
      bf16x8 bf1 = *reinterpret_cast<const bf16x8*>(
          wl1 + (((wave * 2 + 1) * 4 + ks) * 64 + lane) * 8);
      int cbx = ((ks * 64 + lg * 16) ^ rxor) + rbase;
#pragma unroll
      for (int mt = 0; mt < 4; ++mt) {
        bf16x8 xf = *reinterpret_cast<const bf16x8*>(xA + mt * 4096 + cbx);
        acc[mt][0] = __builtin_amdgcn_mfma_f32_16x16x32_bf16(bf0, xf, acc[mt][0], 0, 0, 0);
        acc[mt][1] = __builtin_amdgcn_mfma_f32_16x16x32_bf16(bf1, xf, acc[mt][1], 0, 0, 0);
      }
    }

    // ===== LN stat partials: in-lane 8 per L + lg-butterfly -> plain floats =
    {
      float s[4], q[4];
#pragma unroll
      for (int mt = 0; mt < 4; ++mt) {
        f32x4 a0 = acc[mt][0], a1 = acc[mt][1];
        f32x4 ss = a0 + a1;
        f32x4 qq = a0 * a0 + a1 * a1;
        s[mt] = (ss[0] + ss[1]) + (ss[2] + ss[3]);
        q[mt] = (qq[0] + qq[1]) + (qq[2] + qq[3]);
      }
#pragma unroll
      for (int mt = 0; mt < 4; ++mt) {
        s[mt] += __shfl_xor(s[mt], 16);  q[mt] += __shfl_xor(q[mt], 16);
        s[mt] += __shfl_xor(s[mt], 32);  q[mt] += __shfl_xor(q[mt], 32);
      }
      if (lane < 16) {
#pragma unroll
        for (int mt = 0; mt < 4; ++mt) {
          ssum[wave][mt * 16 + lane] = s[mt];
          qsum[wave][mt * 16 + lane] = q[mt];
        }
      }
    }
    __syncthreads();  // B1: partials visible

    // ===== per-lane combine + normalize + ReLU -> xn b128 (p2l phys) =======
    {
      f32x4 glo = *reinterpret_cast<const f32x4*>(gamma + layer * 128 + wave * 32 + lg * 4);
      f32x4 ghi = *reinterpret_cast<const f32x4*>(gamma + layer * 128 + wave * 32 + 16 + lg * 4);
      f32x4 tlo = *reinterpret_cast<const f32x4*>(beta + layer * 128 + wave * 32 + lg * 4);
      f32x4 thi = *reinterpret_cast<const f32x4*>(beta + layer * 128 + wave * 32 + 16 + lg * 4);
#pragma unroll
      for (int mt = 0; mt < 4; ++mt) {
        int L = mt * 16 + ci;
        float sf = (ssum[0][L] + ssum[1][L]) + (ssum[2][L] + ssum[3][L]);
        float qf = (qsum[0][L] + qsum[1][L]) + (qsum[2][L] + qsum[3][L]);
        float mu = sf * (1.f / 128.f);
        float rs = rsqrtf(qf * (1.f / 128.f) - mu * mu + 1e-5f);
        f32x4 alo = glo * rs, ahi = ghi * rs;
        f32x4 clo = tlo - alo * mu, chi = thi - ahi * mu;
        uint4v w;
#pragma unroll
        for (int r = 0; r < 4; ++r) {
          float ylo = fmaxf(fmaf(acc[mt][0][r], alo[r], clo[r]), 0.f);
          float yhi = fmaxf(fmaf(acc[mt][1][r], ahi[r], chi[r]), 0.f);
          w[r] = pk2(ylo, yhi);
        }
        *reinterpret_cast<uint4v*>(xB + mt * 4096 + wbase) = w;
      }
    }
    __syncthreads();  // B2: xn visible

    // ===== GEMM2 (transposed): acc2[mt][r] = x1[L=mt*16+ci][n2=wave*16+lg*4+r]
    const unsigned short* wl2 = wp2u + (size_t)layer * 8192;
    f32x4 b2v = *reinterpret_cast<const f32x4*>(b2 + layer * 64 + wave * 16 + lg * 4);
    f32x4 acc2[4];
#pragma unroll
    for (int mt = 0; mt < 4; ++mt) acc2[mt] = b2v;
#pragma unroll
    for (int ks = 0; ks < 4; ++ks) {
      bf16x8 wf = *reinterpret_cast<const bf16x8*>(
          wl2 + ((wave * 4 + ks) * 64 + lane) * 8);
      int cbx = ((ks * 64 + lg * 16) ^ rxor) + rbase;
#pragma unroll
      for (int mt = 0; mt < 4; ++mt) {
        bf16x8 xf = *reinterpret_cast<const bf16x8*>(xB + mt * 4096 + cbx);
        acc2[mt] = __builtin_amdgcn_mfma_f32_16x16x32_bf16(wf, xf, acc2[mt], 0, 0, 0);
      }
    }

    // max-pool over L: in-lane over mt, then over ci lanes (shfl 1,2,4,8)
    f32x4 mm;
#pragma unroll
    for (int r = 0; r < 4; ++r)
      mm[r] = fmaxf(fmaxf(acc2[0][r], acc2[1][r]), fmaxf(acc2[2][r], acc2[3][r]));
#pragma unroll
    for (int o = 1; o < 16; o <<= 1)
#pragma unroll
      for (int r = 0; r < 4; ++r) mm[r] = fmaxf(mm[r], __shfl_xor(mm[r], o));

    if (layer < 2) {
      // pack (x1, x2) -> xA (pi2 phys layout): one b128 per mt
      // (xA's only readers finished before B1; no extra barrier needed)
#pragma unroll
      for (int mt = 0; mt < 4; ++mt) {
        uint4v w;
#pragma unroll
        for (int r = 0; r < 4; ++r) w[r] = pk2(acc2[mt][r], mm[r]);
        *reinterpret_cast<uint4v*>(xA + mt * 4096 + wbase) = w;
      }
      __syncthreads();  // B3: new x visible for next layer
    } else {
      // final output (f32): out[b] = [x2_3, x2_3]; mm[r] holds n2=wave*16+lg*4+r
      if (ci == 0) {
        float* o = out + (size_t)blockIdx.x * 128 + wave * 16 + lg * 4;
        *reinterpret_cast<f32x4*>(o) = mm;
        *reinterpret_cast<f32x4*>(o + 64) = mm;
      }
    }
  }
}

extern "C" void kernel_launch(void* const* d_in, const int* in_sizes, int n_in,
                              void* d_out, int out_size, void* d_ws, size_t ws_size,
                              hipStream_t stream) {
  const float* hidden = (const float*)d_in[0];
  const float* W1 = (const float*)d_in[1];
  const float* b1 = (const float*)d_in[2];
  const float* gamma = (const float*)d_in[3];
  const float* beta = (const float*)d_in[4];
  const float* W2 = (const float*)d_in[5];
  const float* b2 = (const float*)d_in[6];
  (void)in_sizes; (void)n_in; (void)out_size; (void)ws_size;

  unsigned short* wp1 = (unsigned short*)d_ws;          // 49152 ushorts
  unsigned short* wp2 = wp1 + 3 * 8 * 4 * 64 * 8;       // 24576 ushorts
  float* out = (float*)d_out;

  repack_w<<<36, 256, 0, stream>>>(W1, W2, wp1, wp2);
  fused_mlp<<<NB, 256, 0, stream>>>(hidden, b1, b2, gamma, beta, wp1, wp2, out);
}

// Round 15
// 144.146 us; speedup vs baseline: 1.8770x; 1.1030x over previous
//
#include <hip/hip_runtime.h>

#define NB 8192
#define NL 64
#define NH 128

typedef __bf16 bf16x8 __attribute__((ext_vector_type(8)));
typedef float f32x4 __attribute__((ext_vector_type(4)));
typedef float f32x2 __attribute__((ext_vector_type(2)));
typedef unsigned short ushort8 __attribute__((ext_vector_type(8)));

// phys->logical permutation for the h buffer (GEMM1 writeback pair-packing):
// phys p = w*32 + ci*2 + half  holds logical  w*32 + half*16 + ci
__device__ __host__ __forceinline__ int p2l(int p) {
  return (p & ~31) + ((p & 1) << 4) + ((p & 31) >> 1);
}
// phys->logical permutation for the x=concat(x1,x2) buffer (x1x2 pair-packing):
// phys even p -> x1 col p/2 ; phys odd p -> x2 col p/2 (logical 64+p/2)
__device__ __host__ __forceinline__ int pi2(int p) {
  return (p & 1) ? 64 + (p >> 1) : (p >> 1);
}

__device__ __forceinline__ unsigned pk2(float lo, float hi) {
  union { __bf16 b[2]; unsigned u; } t;
  t.b[0] = (__bf16)lo; t.b[1] = (__bf16)hi;
  return t.u;
}

// ---------------------------------------------------------------------------
// Repack weights (f32 -> bf16 MFMA-B fragments) + permuted f32 gamma/beta.
// wp1: [layer3][ntile8][kstep4][lane64][reg8]; value = W1[l][srck][n]
//      srck = k (layer 0) | pi2(k) (layers 1,2)   [x-buffer phys layout]
// wp2: [layer3][ntile4][kstep4][lane64][reg8]; value = W2[l][p2l(k)][n]
// gbt: f32 [layer3][2][4(q)][36]; gbt[l][g][q][k] = param[l][p2l(q*32+k)]
// ---------------------------------------------------------------------------
__global__ __launch_bounds__(256) void repack_w(const float* __restrict__ W1,
                                                const float* __restrict__ W2,
                                                const float* __restrict__ gamma,
                                                const float* __restrict__ beta,
                                                unsigned short* __restrict__ wp1,
                                                unsigned short* __restrict__ wp2,
                                                float* __restrict__ gbt) {
  int t = blockIdx.x * 256 + threadIdx.x;
  int lane = t & 63, g = t >> 6;
  if (g < 96) {                                   // W1: 3*8*4 groups
    int layer = g >> 5, rem = g & 31, nt = rem >> 2, ks = rem & 3;
    int n = nt * 16 + (lane & 15);
    int kb = ks * 32 + (lane >> 4) * 8;
    ushort8 v;
#pragma unroll
    for (int r = 0; r < 8; ++r) {
      int k = kb + r;
      int srck = (layer == 0) ? k : pi2(k);
      union { __bf16 b; unsigned short u; } c;
      c.b = (__bf16)W1[(layer * 128 + srck) * 128 + n];
      v[r] = c.u;
    }
    *reinterpret_cast<ushort8*>(wp1 + ((size_t)g * 64 + lane) * 8) = v;
  } else if (g < 144) {                           // W2: 3*4*4 groups, k by p2l
    int g2 = g - 96;
    int layer = g2 >> 4, rem = g2 & 15, nt = rem >> 2, ks = rem & 3;
    int n = nt * 16 + (lane & 15);
    int kb = ks * 32 + (lane >> 4) * 8;
    ushort8 v;
#pragma unroll
    for (int r = 0; r < 8; ++r) {
      union { __bf16 b; unsigned short u; } c;
      c.b = (__bf16)W2[(layer * 128 + p2l(kb + r)) * 64 + n];
      v[r] = c.u;
    }
    *reinterpret_cast<ushort8*>(wp2 + ((size_t)g2 * 64 + lane) * 8) = v;
  } else if (g < 150) {                           // gamma/beta f32, padded
    int g2 = g - 144;                             // 0..5
    int layer = g2 >> 1, param = g2 & 1;
    const float* src = (param == 0 ? gamma : beta) + layer * 128;
    float* dst = gbt + layer * 288 + param * 144;
    int p0 = lane * 2;
#pragma unroll
    for (int u = 0; u < 2; ++u) {
      int p = p0 + u;
      dst[(p >> 5) * 36 + (p & 31)] = src[p2l(p)];
    }
  }
}

// ---------------------------------------------------------------------------
// Fused depth-3 MLP stack, one workgroup (4 waves) per batch row b.
// TWO LDS activation buffers, both bf16 [64][128], 4-bit XOR swizzle
//   byte ^= ((row & 15) << 4)
// xA = x (concat/stage0), xB = h / normalized-h. 3 barriers/layer.
// THE single change vs the 142us R8 kernel: NO W2/b2 prefetch — that +16 VGPR
// pushed arch-VGPR to 76, crossing the measured 64-reg occupancy cliff
// (<=64 -> 4 blocks/CU, 42-43% occ; >=68 -> ~2.6 blocks, 32-33% occ).
// w2f fragments load inside the GEMM2 ks-loop as in the 60-VGPR R7 kernel.
// No min-waves bound (R4/R6: forcing 8 waves/EU spills ~100KB/block).
// ---------------------------------------------------------------------------
__global__ __launch_bounds__(256) void fused_mlp(
    const float* __restrict__ hidden,
    const float* __restrict__ b1,
    const float* __restrict__ b2,
    const unsigned short* __restrict__ wp1u,
    const unsigned short* __restrict__ wp2u,
    const float* __restrict__ gbt,
    float* __restrict__ out) {
  __shared__ __align__(16) unsigned short xAu[NL * NH];    // 16384 B (x)
  __shared__ __align__(16) unsigned short xBu[NL * NH];    // 16384 B (h/xn)
  __shared__ __align__(16) float gbuf[864];                // 3456 B

  const int tid = threadIdx.x;
  const int wave = tid >> 6, lane = tid & 63;
  const int ci = lane & 15, lg = lane >> 4;
  char* xA = reinterpret_cast<char*>(xAu);
  char* xB = reinterpret_cast<char*>(xBu);

  // thread-invariant address pieces for fragment reads
  const int abase = ci * 256;                 // row (=..+ci) byte base (mod tiles)
  const int axor = ci << 4;                   // 4-bit row swizzle for rows ≡ ci

  // stage gamma/beta (f32, padded layout) into LDS
  if (tid < 96) {
#pragma unroll
    for (int u = 0; u < 9; ++u) gbuf[tid * 9 + u] = gbt[tid * 9 + u];
  }

  // ---- stage 0: load hidden[b] (f32) -> xA (bf16, swizzled, identity) ----
  const float* src = hidden + (size_t)blockIdx.x * (NL * NH);
#pragma unroll
  for (int i = 0; i < 4; ++i) {
    int f = i * 256 + tid;          // 8-elem chunk id, 0..1023
    int row = f >> 4;
    int cb = (f & 15) * 16;         // byte column
    const float4* p = reinterpret_cast<const float4*>(src + f * 8);
    float4 a = p[0], bq = p[1];
    bf16x8 v;
    v[0] = (__bf16)a.x;  v[1] = (__bf16)a.y;  v[2] = (__bf16)a.z;  v[3] = (__bf16)a.w;
    v[4] = (__bf16)bq.x; v[5] = (__bf16)bq.y; v[6] = (__bf16)bq.z; v[7] = (__bf16)bq.w;
    *reinterpret_cast<bf16x8*>(xA + row * 256 + (cb ^ ((row & 15) << 4))) = v;
  }
  __syncthreads();

  for (int layer = 0; layer < 3; ++layer) {
    const unsigned short* wl1 = wp1u + (size_t)layer * 16384;
    const float bv0 = b1[layer * 128 + wave * 32 + ci];
    const float bv1 = b1[layer * 128 + wave * 32 + 16 + ci];
    const int dby = (wave * 16 + ci) * 4;

    // ========== GEMM1: h = x @ W1 + b1 (bias in C-init; wave -> 32 cols) ====
    f32x4 acc[4][2];
#pragma unroll
    for (int mt = 0; mt < 4; ++mt) {
      acc[mt][0] = f32x4{bv0, bv0, bv0, bv0};
      acc[mt][1] = f32x4{bv1, bv1, bv1, bv1};
    }
#pragma unroll
    for (int ks = 0; ks < 4; ++ks) {
      bf16x8 bf0 = *reinterpret_cast<const bf16x8*>(
          wl1 + (((wave * 2 + 0) * 4 + ks) * 64 + lane) * 8);
      bf16x8 bf1 = *reinterpret_cast<const bf16x8*>(
          wl1 + (((wave * 2 + 1) * 4 + ks) * 64 + lane) * 8);
      int cbx = ((ks * 64 + lg * 16) ^ axor) + abase;
#pragma unroll
      for (int mt = 0; mt < 4; ++mt) {
        bf16x8 af = *reinterpret_cast<const bf16x8*>(xA + mt * 4096 + cbx);
        acc[mt][0] = __builtin_amdgcn_mfma_f32_16x16x32_bf16(af, bf0, acc[mt][0], 0, 0, 0);
        acc[mt][1] = __builtin_amdgcn_mfma_f32_16x16x32_bf16(af, bf1, acc[mt][1], 0, 0, 0);
      }
    }
    // writeback h -> xB (no barrier needed: xB has no pending readers)
    // row&15 = lg*4+r, so the swizzle is compile-time per (lg,r)
#pragma unroll
    for (int mt = 0; mt < 4; ++mt)
#pragma unroll
      for (int r = 0; r < 4; ++r) {
        int row = mt * 16 + lg * 4 + r;
        *reinterpret_cast<unsigned*>(
            xB + row * 256 + (dby ^ ((lg * 4 + r) << 4))) =
            pk2(acc[mt][0][r], acc[mt][1][r]);
      }
    __syncthreads();  // β1: h visible to LN

    // ========== LayerNorm + ReLU on xB in place: 4 threads per row ==========
    {
      const int row = wave * 16 + (lane >> 2);
      const int q = lane & 3;
      const int rb = row * 256, rx = (lane >> 2) << 4;
      bf16x8 h0 = *reinterpret_cast<const bf16x8*>(xB + rb + ((q * 64 + 0) ^ rx));
      bf16x8 h1 = *reinterpret_cast<const bf16x8*>(xB + rb + ((q * 64 + 16) ^ rx));
      bf16x8 h2 = *reinterpret_cast<const bf16x8*>(xB + rb + ((q * 64 + 32) ^ rx));
      bf16x8 h3 = *reinterpret_cast<const bf16x8*>(xB + rb + ((q * 64 + 48) ^ rx));
      f32x2 f[16];
#pragma unroll
      for (int cch = 0; cch < 4; ++cch) {
        bf16x8 hv = (cch == 0) ? h0 : (cch == 1) ? h1 : (cch == 2) ? h2 : h3;
#pragma unroll
        for (int j2 = 0; j2 < 4; ++j2)
          f[cch * 4 + j2] = f32x2{(float)hv[j2 * 2], (float)hv[j2 * 2 + 1]};
      }
      f32x2 s2 = {0.f, 0.f}, q2 = {0.f, 0.f};
#pragma unroll
      for (int i = 0; i < 16; ++i) { s2 += f[i]; q2 += f[i] * f[i]; }
      float s = s2.x + s2.y, sq = q2.x + q2.y;
      s += __shfl_xor(s, 1);  sq += __shfl_xor(sq, 1);
      s += __shfl_xor(s, 2);  sq += __shfl_xor(sq, 2);
      float mu = s * (1.f / 128.f);
      float var = sq * (1.f / 128.f) - mu * mu;
      float rs = rsqrtf(var + 1e-5f);
      const f32x2* gl = reinterpret_cast<const f32x2*>(gbuf + layer * 288 + q * 36);
      const f32x2* bl = reinterpret_cast<const f32x2*>(gbuf + layer * 288 + 144 + q * 36);
#pragma unroll
      for (int cch = 0; cch < 4; ++cch) {
        union { unsigned u[4]; bf16x8 v; } yy;
#pragma unroll
        for (int j2 = 0; j2 < 4; ++j2) {
          int i = cch * 4 + j2;
          f32x2 a2 = gl[i] * rs;
          f32x2 c2 = bl[i] - a2 * mu;
          f32x2 y2 = f[i] * a2 + c2;
          yy.u[j2] = pk2(fmaxf(y2.x, 0.f), fmaxf(y2.y, 0.f));
        }
        *reinterpret_cast<bf16x8*>(xB + rb + ((q * 64 + cch * 16) ^ rx)) = yy.v;
      }
    }
    __syncthreads();  // β2: normalized x visible

    // ========== GEMM2: x1 = xn @ W2 + b2 (bias in C-init; wave -> 16 cols) ==
    const unsigned short* wl2 = wp2u + (size_t)layer * 8192;
    f32x4 acc2[4];
    {
      float b2v = b2[layer * 64 + wave * 16 + ci];
#pragma unroll
      for (int mt = 0; mt < 4; ++mt) acc2[mt] = f32x4{b2v, b2v, b2v, b2v};
    }
#pragma unroll
    for (int ks = 0; ks < 4; ++ks) {
      bf16x8 bfr = *reinterpret_cast<const bf16x8*>(
          wl2 + ((wave * 4 + ks) * 64 + lane) * 8);
      int cbx = ((ks * 64 + lg * 16) ^ axor) + abase;
#pragma unroll
      for (int mt = 0; mt < 4; ++mt) {
        bf16x8 af = *reinterpret_cast<const bf16x8*>(xB + mt * 4096 + cbx);
        acc2[mt] = __builtin_amdgcn_mfma_f32_16x16x32_bf16(af, bfr, acc2[mt], 0, 0, 0);
      }
    }

    // column max over all 64 rows: in-reg + 2 shuffles (lane holds col wave*16+ci)
    float mm;
    {
      float m = -3.0e38f;
#pragma unroll
      for (int mt = 0; mt < 4; ++mt)
#pragma unroll
        for (int r = 0; r < 4; ++r) m = fmaxf(m, acc2[mt][r]);
      m = fmaxf(m, __shfl_xor(m, 16));
      m = fmaxf(m, __shfl_xor(m, 32));
      mm = m;
    }

    if (layer < 2) {
      // pack (x1[row][c], x2[c]) -> xA phys dword d = wave*16+ci
      // (xA's readers all finished before β1; no extra barrier needed)
#pragma unroll
      for (int mt = 0; mt < 4; ++mt)
#pragma unroll
        for (int r = 0; r < 4; ++r) {
          int row = mt * 16 + lg * 4 + r;
          *reinterpret_cast<unsigned*>(
              xA + row * 256 + (dby ^ ((lg * 4 + r) << 4))) =
              pk2(acc2[mt][r], mm);
        }
      __syncthreads();  // β3: new x visible for next layer
    } else {
      // final output (f32): out[b] = [x2_3, x2_3]
      if (lg == 0) {
        size_t o = (size_t)blockIdx.x * 128 + wave * 16 + ci;
        out[o] = mm;
        out[o + 64] = mm;
      }
    }
  }
}

extern "C" void kernel_launch(void* const* d_in, const int* in_sizes, int n_in,
                              void* d_out, int out_size, void* d_ws, size_t ws_size,
                              hipStream_t stream) {
  const float* hidden = (const float*)d_in[0];
  const float* W1 = (const float*)d_in[1];
  const float* b1 = (const float*)d_in[2];
  const float* gamma = (const float*)d_in[3];
  const float* beta = (const float*)d_in[4];
  const float* W2 = (const float*)d_in[5];
  const float* b2 = (const float*)d_in[6];
  (void)in_sizes; (void)n_in; (void)out_size; (void)ws_size;

  unsigned short* wp1 = (unsigned short*)d_ws;          // 49152 ushorts
  unsigned short* wp2 = wp1 + 3 * 8 * 4 * 64 * 8;       // 24576 ushorts
  float* gbt = (float*)(wp2 + 3 * 4 * 4 * 64 * 8);      // 864 f32 (padded)
  float* out = (float*)d_out;

  repack_w<<<38, 256, 0, stream>>>(W1, W2, gamma, beta, wp1, wp2, gbt);
  fused_mlp<<<NB, 256, 0, stream>>>(hidden, b1, b2, wp1, wp2, gbt, out);
}